// Round 1
// baseline (273.721 us; speedup 1.0000x reference)
//
#include <hip/hip_runtime.h>
#include <stdint.h>

// Problem constants: B=1, R=128, L=256, IN=128, DM=32, DIM=128
// out[i,j,k] = x[i,j,k] + (1/R)*sum_{r,c,d} mp[r,j,c]*mp[r,i,d]*W2[k,c*32+d] + b2[k]
// mp[r,i,d] = sum_e m[r,i,e]*W1[d,e] + b1[d]

typedef __attribute__((ext_vector_type(8))) short bf16x8;
typedef __attribute__((ext_vector_type(4))) float f32x4;

#define MFMA16 __builtin_amdgcn_mfma_f32_16x16x32_bf16

__device__ __forceinline__ unsigned short f2bf(float f) {
    union { float f; unsigned int u; } x; x.f = f;
    unsigned int r = (x.u + 0x7fffu + ((x.u >> 16) & 1u)) >> 16;  // RNE
    return (unsigned short)r;
}

__device__ __forceinline__ bf16x8 load8f_bf(const float* p) {
    float4 v0 = *(const float4*)p;
    float4 v1 = *(const float4*)(p + 4);
    union { bf16x8 v; unsigned short u[8]; } r;
    r.u[0] = f2bf(v0.x); r.u[1] = f2bf(v0.y); r.u[2] = f2bf(v0.z); r.u[3] = f2bf(v0.w);
    r.u[4] = f2bf(v1.x); r.u[5] = f2bf(v1.y); r.u[6] = f2bf(v1.z); r.u[7] = f2bf(v1.w);
    return r.v;
}

// ---------------------------------------------------------------------------
// prep: mpT[(i*32+d)*128 + r] = bf16(mp[r,i,d]);  W2bf[k*1024+cd] = bf16(W2)
// blocks 0..511: mp GEMM via MFMA (wave = one (i, r-tile of 16), n = 32 d's)
// blocks 512..639: W2 cast (32768 float4s)
// ---------------------------------------------------------------------------
__global__ __launch_bounds__(256) void prep_kernel(
    const float* __restrict__ m, const float* __restrict__ W1,
    const float* __restrict__ pb1, const float* __restrict__ W2,
    unsigned short* __restrict__ mpT, unsigned short* __restrict__ W2bf)
{
    const int bx = blockIdx.x;
    if (bx >= 512) {
        const int t = (bx - 512) * 256 + threadIdx.x;  // 0..32767
        float4 v = ((const float4*)W2)[t];
        ushort4 o;
        o.x = f2bf(v.x); o.y = f2bf(v.y); o.z = f2bf(v.z); o.w = f2bf(v.w);
        ((ushort4*)W2bf)[t] = o;
        return;
    }
    const int lane = threadIdx.x & 63;
    const int w    = threadIdx.x >> 6;
    const int ln   = lane & 15, q = lane >> 4;
    const int tile = bx * 4 + w;          // 0..2047
    const int i    = tile >> 3;           // 0..255
    const int r0   = (tile & 7) * 16;     // r-tile base

    // A-frag: A[rr=ln][e] = m[(r0+ln), i, e]; B-frag: B[n=d=ln(+16)][e] = W1[d][e]
    const float* Ap  = m  + ((size_t)(r0 + ln) * 256 + i) * 128 + q * 8;
    const float* Bp0 = W1 + (size_t)ln * 128 + q * 8;
    const float* Bp1 = W1 + (size_t)(16 + ln) * 128 + q * 8;

    f32x4 acc0 = {0.f, 0.f, 0.f, 0.f};
    f32x4 acc1 = {0.f, 0.f, 0.f, 0.f};
    #pragma unroll
    for (int ke = 0; ke < 4; ++ke) {
        bf16x8 a  = load8f_bf(Ap  + ke * 32);
        bf16x8 b0 = load8f_bf(Bp0 + ke * 32);
        bf16x8 b1 = load8f_bf(Bp1 + ke * 32);
        acc0 = MFMA16(a, b0, acc0, 0, 0, 0);
        acc1 = MFMA16(a, b1, acc1, 0, 0, 0);
    }
    const float bb0 = pb1[ln];
    const float bb1 = pb1[16 + ln];
    // D layout: row(q*4+reg)=r-in-tile, col(ln)=d. 4 consecutive r -> one 8B store.
    ushort4 o0, o1;
    o0.x = f2bf(acc0[0] + bb0); o0.y = f2bf(acc0[1] + bb0);
    o0.z = f2bf(acc0[2] + bb0); o0.w = f2bf(acc0[3] + bb0);
    o1.x = f2bf(acc1[0] + bb1); o1.y = f2bf(acc1[1] + bb1);
    o1.z = f2bf(acc1[2] + bb1); o1.w = f2bf(acc1[3] + bb1);
    *(ushort4*)(mpT + (size_t)(i * 32 + ln) * 128 + r0 + q * 4)      = o0;
    *(ushort4*)(mpT + (size_t)(i * 32 + 16 + ln) * 128 + r0 + q * 4) = o1;
}

// ---------------------------------------------------------------------------
// fused: per block: i-tile of 8, j-tile of 4 (32 pairs).
// Step B: G[m=(tj,c)][n=(ti,d)] (128x256, K=r=128) via MFMA, acc 64 f32/lane.
// G -> LDS bf16 in [pair p][cd] layout (32x1024 hw = 64 KB) with chunk-XOR
// swizzle (chunk ^= p&7) so b128 A-frag reads are ~2-way (free).
// Step C: O[p][kout] (32x128, K=1024) via MFMA, B-frags from L2-resident W2bf.
// Epilogue: out = x + O/128 + b2.
// ---------------------------------------------------------------------------
__global__ __launch_bounds__(512, 4) void fused_kernel(
    const float* __restrict__ x, const float* __restrict__ b2,
    const unsigned short* __restrict__ mpT, const unsigned short* __restrict__ W2bf,
    float* __restrict__ out)
{
    __shared__ __align__(16) unsigned short Gl[32 * 1024];  // exactly 64 KB

    const int tid  = threadIdx.x;
    const int lane = tid & 63, w = tid >> 6;
    const int ln   = lane & 15, q = lane >> 4;
    const int wm   = w >> 2, wn = w & 3;

    const int i0 = blockIdx.x * 8;    // gridDim.x = 32
    const int j0 = blockIdx.y * 4;    // gridDim.y = 64
    const int irow0 = i0 * 32;        // mpT rows for B operand (n = ti*32+d)
    const int jrow0 = j0 * 32;        // mpT rows for A operand (m = tj*32+c)

    // ---------------- step B ----------------
    const int m0 = wm * 64, n0 = wn * 64;   // wave's 64x64 region of 128x256
    const unsigned short* Ab = mpT + (size_t)(jrow0 + m0 + ln) * 128 + q * 8;
    const unsigned short* Bb = mpT + (size_t)(irow0 + n0 + ln) * 128 + q * 8;

    f32x4 acc[4][4];
    #pragma unroll
    for (int a = 0; a < 4; ++a)
        #pragma unroll
        for (int b = 0; b < 4; ++b)
            acc[a][b] = (f32x4){0.f, 0.f, 0.f, 0.f};

    #pragma unroll
    for (int ks = 0; ks < 4; ++ks) {
        bf16x8 av[4], bv[4];
        #pragma unroll
        for (int t = 0; t < 4; ++t)
            av[t] = *(const bf16x8*)(Ab + (size_t)t * 16 * 128 + ks * 32);
        #pragma unroll
        for (int t = 0; t < 4; ++t)
            bv[t] = *(const bf16x8*)(Bb + (size_t)t * 16 * 128 + ks * 32);
        #pragma unroll
        for (int am = 0; am < 4; ++am)
            #pragma unroll
            for (int bn = 0; bn < 4; ++bn)
                acc[am][bn] = MFMA16(av[am], bv[bn], acc[am][bn], 0, 0, 0);
    }

    // write G tile to LDS as bf16, [p][cd] with chunk swizzle
    #pragma unroll
    for (int am = 0; am < 4; ++am) {
        const int mbase = m0 + am * 16;        // mult of 16 -> tj const below
        const int tj    = mbase >> 5;
        const int cbase = mbase & 31;          // 0 or 16
        #pragma unroll
        for (int bn = 0; bn < 4; ++bn) {
            const int nbase = n0 + bn * 16;
            const int ti    = nbase >> 5;
            const int dbase = nbase & 31;      // 0 or 16
            const int p  = ti * 4 + tj;
            const int p7 = p & 7;
            const int d  = dbase + ln;         // no carry: dbase in {0,16}, ln<16
            const int dz = d >> 3, dlow = d & 7;
            unsigned short* gp = &Gl[p * 1024];
            #pragma unroll
            for (int rg = 0; rg < 4; ++rg) {
                const int c     = cbase + q * 4 + rg;   // no carry
                const int chunk = c * 4 + dz;           // cd>>3
                gp[((chunk ^ p7) << 3) + dlow] = f2bf(acc[am][bn][rg]);
            }
        }
    }
    __syncthreads();

    // ---------------- step C ----------------
    // wave: m-tile mt=wm (pairs mt*16..+15), n-tiles wn and wn+4 (kout 16 each)
    const int pc  = wm * 16 + ln;
    const int pc7 = pc & 7;
    const unsigned short* gp  = &Gl[pc * 1024];
    const unsigned short* wp0 = W2bf + (size_t)(wn * 16 + ln) * 1024 + q * 8;
    const unsigned short* wp1 = W2bf + (size_t)((wn + 4) * 16 + ln) * 1024 + q * 8;

    f32x4 c0 = {0.f, 0.f, 0.f, 0.f};
    f32x4 c1 = {0.f, 0.f, 0.f, 0.f};
    #pragma unroll 8
    for (int ks = 0; ks < 32; ++ks) {
        const int chunk = ks * 4 + q;
        bf16x8 ag = *(const bf16x8*)(gp + ((chunk ^ pc7) << 3));
        bf16x8 w0 = *(const bf16x8*)(wp0 + ks * 32);
        bf16x8 w1 = *(const bf16x8*)(wp1 + ks * 32);
        c0 = MFMA16(ag, w0, c0, 0, 0, 0);
        c1 = MFMA16(ag, w1, c1, 0, 0, 0);
    }

    // ---------------- epilogue ----------------
    const float invR  = 1.0f / 128.0f;
    const int   kout0 = wn * 16 + ln;
    const int   kout1 = (wn + 4) * 16 + ln;
    const float bb0 = b2[kout0];
    const float bb1 = b2[kout1];
    #pragma unroll
    for (int rg = 0; rg < 4; ++rg) {
        const int pp  = wm * 16 + q * 4 + rg;  // D row = pair index
        const int tii = pp >> 2, tjj = pp & 3;
        const size_t base = ((size_t)(i0 + tii) * 256 + (j0 + tjj)) * 128;
        out[base + kout0] = x[base + kout0] + c0[rg] * invR + bb0;
        out[base + kout1] = x[base + kout1] + c1[rg] * invR + bb1;
    }
}

extern "C" void kernel_launch(void* const* d_in, const int* in_sizes, int n_in,
                              void* d_out, int out_size, void* d_ws, size_t ws_size,
                              hipStream_t stream) {
    const float* x  = (const float*)d_in[0];
    const float* m  = (const float*)d_in[1];
    const float* W1 = (const float*)d_in[2];
    const float* b1 = (const float*)d_in[3];
    const float* W2 = (const float*)d_in[4];
    const float* b2 = (const float*)d_in[5];
    float* out = (float*)d_out;

    unsigned short* mpT  = (unsigned short*)d_ws;                 // 8192*128 bf16 = 2 MB
    unsigned short* W2bf = mpT + (size_t)8192 * 128;              // 128*1024 bf16 = 256 KB

    prep_kernel<<<dim3(640), dim3(256), 0, stream>>>(m, W1, b1, W2, mpT, W2bf);
    fused_kernel<<<dim3(32, 64), dim3(512), 0, stream>>>(x, b2, mpT, W2bf, out);
}

// Round 2
// 173.282 us; speedup vs baseline: 1.5796x; 1.5796x over previous
//
#include <hip/hip_runtime.h>
#include <stdint.h>

// B=1, R=128, L=256, IN=128, DM=32, DIM=128
// out[i,j,k] = x[i,j,k] + (1/R)*sum_{r,c,d} mp[r,j,c]*mp[r,i,d]*W2[k,c*32+d] + b2[k]
// mp[r,i,d]  = sum_e m[r,i,e]*W1[d,e] + b1[d]
//
// Layouts (fragment-order, so wave loads are contiguous 1KB):
//  mpF[rt][kr][lane][j]  rt=(i*32+d)>>4 (512), kr=r>>5 (4):
//      value mp[r = kr*32 + (lane>>4)*8 + j][row = rt*16 + (lane&15)]
//  W2f[nt][kc][lane][j]  nt=kout>>4 (8), kc=d (32):
//      value W2t[kout=nt*16+(lane&15)][cd' = kc*32 + (lane>>4)*8 + j],
//      W2t[k][d*32+c] = W2[k][c*32+d]
//  G in LDS per pass (d-half): kloc = d''*32 + c (512), chunk = kloc>>3,
//      addr_h = chunk*264 + (p ^ (chunk>>3))*8 + (kloc&7)

typedef __attribute__((ext_vector_type(8))) short bf16x8;
typedef __attribute__((ext_vector_type(4))) float f32x4;

#define MFMA16 __builtin_amdgcn_mfma_f32_16x16x32_bf16

__device__ __forceinline__ unsigned short f2bf(float f) {
    union { float f; unsigned int u; } x; x.f = f;
    unsigned int r = (x.u + 0x7fffu + ((x.u >> 16) & 1u)) >> 16;  // RNE
    return (unsigned short)r;
}

__device__ __forceinline__ bf16x8 load8f_bf(const float* p) {
    float4 v0 = *(const float4*)p;
    float4 v1 = *(const float4*)(p + 4);
    union { bf16x8 v; unsigned short u[8]; } r;
    r.u[0] = f2bf(v0.x); r.u[1] = f2bf(v0.y); r.u[2] = f2bf(v0.z); r.u[3] = f2bf(v0.w);
    r.u[4] = f2bf(v1.x); r.u[5] = f2bf(v1.y); r.u[6] = f2bf(v1.z); r.u[7] = f2bf(v1.w);
    return r.v;
}

// ---------------------------------------------------------------------------
// prep: blocks 0..511 -> mp GEMM -> mpF (fragment order)
//       blocks 512..575 -> W2 -> W2f (transposed to cd'=d*32+c, fragment order)
// ---------------------------------------------------------------------------
__global__ __launch_bounds__(256) void prep_kernel(
    const float* __restrict__ m, const float* __restrict__ W1,
    const float* __restrict__ pb1, const float* __restrict__ W2,
    unsigned short* __restrict__ mpF, unsigned short* __restrict__ W2f)
{
    const int bx = blockIdx.x;
    if (bx >= 512) {
        const int t    = (bx - 512) * 256 + threadIdx.x;   // 0..16383
        const int nt   = t >> 11;
        const int kc   = (t >> 6) & 31;
        const int lane = t & 63;
        const int ln   = lane & 15, q = lane >> 4;
        const float* src = W2 + (size_t)(nt * 16 + ln) * 1024 + kc;
        union { bf16x8 v; unsigned short u[8]; } r;
        #pragma unroll
        for (int j = 0; j < 8; ++j)
            r.u[j] = f2bf(src[(q * 8 + j) * 32]);
        *(bf16x8*)(W2f + (size_t)t * 8) = r.v;
        return;
    }
    const int lane = threadIdx.x & 63;
    const int w    = threadIdx.x >> 6;
    const int ln   = lane & 15, q = lane >> 4;
    const int tile = bx * 4 + w;          // 0..2047
    const int i    = tile >> 3;           // 0..255
    const int r0   = (tile & 7) * 16;     // r-tile base

    const float* Ap  = m  + ((size_t)(r0 + ln) * 256 + i) * 128 + q * 8;
    const float* Bp0 = W1 + (size_t)ln * 128 + q * 8;
    const float* Bp1 = W1 + (size_t)(16 + ln) * 128 + q * 8;

    f32x4 acc0 = {0.f, 0.f, 0.f, 0.f};
    f32x4 acc1 = {0.f, 0.f, 0.f, 0.f};
    #pragma unroll
    for (int ke = 0; ke < 4; ++ke) {
        bf16x8 a  = load8f_bf(Ap  + ke * 32);
        bf16x8 b0 = load8f_bf(Bp0 + ke * 32);
        bf16x8 b1 = load8f_bf(Bp1 + ke * 32);
        acc0 = MFMA16(a, b0, acc0, 0, 0, 0);
        acc1 = MFMA16(a, b1, acc1, 0, 0, 0);
    }
    const float bb0 = pb1[ln];
    const float bb1 = pb1[16 + ln];
    // D: row=q*4+rg = r-offset in 16-tile, col=ln = d (acc0: d=ln, acc1: d=16+ln)
    const int kr = r0 >> 5;
    const int qr = ((r0 >> 4) & 1) * 2 + (q >> 1);
    const int j0 = (q & 1) * 4;
    const size_t off0 = (size_t)(i * 2 + 0) * 2048 + kr * 512 + (qr * 16 + ln) * 8 + j0;
    const size_t off1 = (size_t)(i * 2 + 1) * 2048 + kr * 512 + (qr * 16 + ln) * 8 + j0;
    ushort4 o0, o1;
    o0.x = f2bf(acc0[0] + bb0); o0.y = f2bf(acc0[1] + bb0);
    o0.z = f2bf(acc0[2] + bb0); o0.w = f2bf(acc0[3] + bb0);
    o1.x = f2bf(acc1[0] + bb1); o1.y = f2bf(acc1[1] + bb1);
    o1.z = f2bf(acc1[2] + bb1); o1.w = f2bf(acc1[3] + bb1);
    *(ushort4*)(mpF + off0) = o0;
    *(ushort4*)(mpF + off1) = o1;
}

// ---------------------------------------------------------------------------
// fused: block = i-tile 8 x j-tile 4 (32 pairs). Two passes over d-halves.
//  step B per pass: G[m=(tj,c) 128][n=(ti,d'') 128], K=128; 8 waves = wm(4)xwn(2)
//  step C per pass: out[p 32][kout 128] += G·W2t over kloc 512; wave w = kout-tile
// ---------------------------------------------------------------------------
__global__ __launch_bounds__(512, 6) void fused_kernel(
    const float* __restrict__ x, const float* __restrict__ b2,
    const unsigned short* __restrict__ mpF, const unsigned short* __restrict__ W2f,
    float* __restrict__ out)
{
    __shared__ __align__(16) unsigned short Gl[64 * 264];  // 33792 B

    const int tid  = threadIdx.x;
    const int lane = tid & 63, w = tid >> 6;
    const int ln   = lane & 15, q = lane >> 4;
    const int wm   = w & 3, wn = w >> 2;      // step B: tj=wm, ti base=wn*4

    const int i0 = blockIdx.x * 8;            // gridDim.x = 32
    const int j0 = blockIdx.y * 4;            // gridDim.y = 64

    f32x4 cacc0 = {0.f, 0.f, 0.f, 0.f};
    f32x4 cacc1 = {0.f, 0.f, 0.f, 0.f};

    const unsigned short* wbase = W2f + (size_t)(w * 32) * 512 + lane * 8;

    #pragma unroll
    for (int pass = 0; pass < 2; ++pass) {
        // ---------------- step B ----------------
        f32x4 acc[2][4];
        #pragma unroll
        for (int a = 0; a < 2; ++a)
            #pragma unroll
            for (int b = 0; b < 4; ++b)
                acc[a][b] = (f32x4){0.f, 0.f, 0.f, 0.f};

        const unsigned short* Abase = mpF + (size_t)((j0 + wm) * 2) * 2048 + lane * 8;
        const unsigned short* Bbase = mpF + (size_t)((i0 + wn * 4) * 2 + pass) * 2048 + lane * 8;

        #pragma unroll
        for (int ks = 0; ks < 4; ++ks) {
            bf16x8 av[2], bv[4];
            av[0] = *(const bf16x8*)(Abase + ks * 512);
            av[1] = *(const bf16x8*)(Abase + 2048 + ks * 512);
            #pragma unroll
            for (int bn = 0; bn < 4; ++bn)
                bv[bn] = *(const bf16x8*)(Bbase + (size_t)bn * 4096 + ks * 512);
            #pragma unroll
            for (int am = 0; am < 2; ++am)
                #pragma unroll
                for (int bn = 0; bn < 4; ++bn)
                    acc[am][bn] = MFMA16(av[am], bv[bn], acc[am][bn], 0, 0, 0);
        }

        // G -> LDS: value (p = ti*4+tj, kloc = d''*32 + c), b64 stores, ~2-way
        #pragma unroll
        for (int am = 0; am < 2; ++am) {
            const int chunk = ln * 4 + am * 2 + (q >> 1);   // d''=ln, c>>3
            const int sig   = chunk >> 3;
            const int hbase = chunk * 264 + (q & 1) * 4;
            #pragma unroll
            for (int bn = 0; bn < 4; ++bn) {
                const int p  = (wn * 4 + bn) * 4 + wm;
                const int pp = p ^ sig;
                ushort4 g;
                g.x = f2bf(acc[am][bn][0]); g.y = f2bf(acc[am][bn][1]);
                g.z = f2bf(acc[am][bn][2]); g.w = f2bf(acc[am][bn][3]);
                *(ushort4*)(Gl + hbase + pp * 8) = g;
            }
        }
        __syncthreads();

        // ---------------- step C ----------------
        const unsigned short* wp = wbase + (size_t)(pass * 16) * 512;
        #pragma unroll 4
        for (int ks = 0; ks < 16; ++ks) {
            const int chunk = ks * 4 + q;
            const int sig   = chunk >> 3;                   // const within instr
            const unsigned short* gp = Gl + chunk * 264 + (ln ^ sig) * 8;
            bf16x8 ag0 = *(const bf16x8*)gp;                // pairs 0..15
            bf16x8 ag1 = *(const bf16x8*)(gp + 128);        // pairs 16..31
            bf16x8 wv  = *(const bf16x8*)(wp + ks * 512);
            cacc0 = MFMA16(ag0, wv, cacc0, 0, 0, 0);
            cacc1 = MFMA16(ag1, wv, cacc1, 0, 0, 0);
        }
        if (pass == 0) __syncthreads();
    }

    // ---------------- epilogue ----------------
    const float invR = 1.0f / 128.0f;
    const int   k    = w * 16 + ln;
    const float bb   = b2[k];
    #pragma unroll
    for (int rg = 0; rg < 4; ++rg) {
        {
            const int p = q * 4 + rg;                        // mt = 0
            const size_t base = ((size_t)(i0 + (p >> 2)) * 256 + (j0 + (p & 3))) * 128;
            out[base + k] = x[base + k] + cacc0[rg] * invR + bb;
        }
        {
            const int p = 16 + q * 4 + rg;                   // mt = 1
            const size_t base = ((size_t)(i0 + (p >> 2)) * 256 + (j0 + (p & 3))) * 128;
            out[base + k] = x[base + k] + cacc1[rg] * invR + bb;
        }
    }
}

extern "C" void kernel_launch(void* const* d_in, const int* in_sizes, int n_in,
                              void* d_out, int out_size, void* d_ws, size_t ws_size,
                              hipStream_t stream) {
    const float* x  = (const float*)d_in[0];
    const float* m  = (const float*)d_in[1];
    const float* W1 = (const float*)d_in[2];
    const float* b1 = (const float*)d_in[3];
    const float* W2 = (const float*)d_in[4];
    const float* b2 = (const float*)d_in[5];
    float* out = (float*)d_out;

    unsigned short* mpF = (unsigned short*)d_ws;               // 512*2048 h = 2 MB
    unsigned short* W2f = mpF + (size_t)512 * 2048;            // 131072 h = 256 KB

    prep_kernel<<<dim3(576), dim3(256), 0, stream>>>(m, W1, b1, W2, mpF, W2f);
    fused_kernel<<<dim3(32, 64), dim3(512), 0, stream>>>(x, b2, mpF, W2f, out);
}

// Round 4
// 149.855 us; speedup vs baseline: 1.8266x; 1.1563x over previous
//
#include <hip/hip_runtime.h>
#include <stdint.h>

// B=1, R=128, L=256, IN=128, DM=32, DIM=128
// out[i,j,k] = x[i,j,k] + (1/R)*sum_{r,c,d} mp[r,j,c]*mp[r,i,d]*W2[k,c*32+d] + b2[k]
// mp[r,i,d]  = sum_e m[r,i,e]*W1[d,e] + b1[d]
//
// mpF[rt][kr][lane][j]  rt=(i*32+d)>>4 (512), kr=r>>5 (4):
//     value mp[r = kr*32 + (lane>>4)*8 + j][row = rt*16 + (lane&15)]
// W2f[nt][kc][lane][j]  nt=kout>>4 (8), kc=d (32):
//     value W2t[kout=nt*16+(lane&15)][cd' = kc*32 + (lane>>4)*8 + j]
// G in LDS per pass (d-half): kloc = d''*32 + c (512), chunk = kloc>>3,
//     addr_h = chunk*264 + (p ^ (chunk>>3))*8 + (kloc&7)

typedef __attribute__((ext_vector_type(8))) short bf16x8;
typedef __attribute__((ext_vector_type(4))) float f32x4;

#define MFMA16 __builtin_amdgcn_mfma_f32_16x16x32_bf16

__device__ __forceinline__ unsigned short f2bf(float f) {
    union { float f; unsigned int u; } x; x.f = f;
    unsigned int r = (x.u + 0x7fffu + ((x.u >> 16) & 1u)) >> 16;  // RNE
    return (unsigned short)r;
}

__device__ __forceinline__ bf16x8 load8f_bf(const float* p) {
    float4 v0 = *(const float4*)p;
    float4 v1 = *(const float4*)(p + 4);
    union { bf16x8 v; unsigned short u[8]; } r;
    r.u[0] = f2bf(v0.x); r.u[1] = f2bf(v0.y); r.u[2] = f2bf(v0.z); r.u[3] = f2bf(v0.w);
    r.u[4] = f2bf(v1.x); r.u[5] = f2bf(v1.y); r.u[6] = f2bf(v1.z); r.u[7] = f2bf(v1.w);
    return r.v;
}

// ---------------------------------------------------------------------------
// prep: blocks 0..511 -> mp GEMM -> mpF; blocks 512..575 -> W2 -> W2f
// ---------------------------------------------------------------------------
__global__ __launch_bounds__(256) void prep_kernel(
    const float* __restrict__ m, const float* __restrict__ W1,
    const float* __restrict__ pb1, const float* __restrict__ W2,
    unsigned short* __restrict__ mpF, unsigned short* __restrict__ W2f)
{
    const int bx = blockIdx.x;
    if (bx >= 512) {
        const int t    = (bx - 512) * 256 + threadIdx.x;   // 0..16383
        const int nt   = t >> 11;
        const int kc   = (t >> 6) & 31;
        const int lane = t & 63;
        const int ln   = lane & 15, q = lane >> 4;
        const float* src = W2 + (size_t)(nt * 16 + ln) * 1024 + kc;
        union { bf16x8 v; unsigned short u[8]; } r;
        #pragma unroll
        for (int j = 0; j < 8; ++j)
            r.u[j] = f2bf(src[(q * 8 + j) * 32]);
        *(bf16x8*)(W2f + (size_t)t * 8) = r.v;
        return;
    }
    const int lane = threadIdx.x & 63;
    const int w    = threadIdx.x >> 6;
    const int ln   = lane & 15, q = lane >> 4;
    const int tile = bx * 4 + w;          // 0..2047
    const int i    = tile >> 3;           // 0..255
    const int r0   = (tile & 7) * 16;     // r-tile base

    const float* Ap  = m  + ((size_t)(r0 + ln) * 256 + i) * 128 + q * 8;
    const float* Bp0 = W1 + (size_t)ln * 128 + q * 8;
    const float* Bp1 = W1 + (size_t)(16 + ln) * 128 + q * 8;

    f32x4 acc0 = {0.f, 0.f, 0.f, 0.f};
    f32x4 acc1 = {0.f, 0.f, 0.f, 0.f};
    #pragma unroll
    for (int ke = 0; ke < 4; ++ke) {
        bf16x8 a  = load8f_bf(Ap  + ke * 32);
        bf16x8 b0 = load8f_bf(Bp0 + ke * 32);
        bf16x8 b1 = load8f_bf(Bp1 + ke * 32);
        acc0 = MFMA16(a, b0, acc0, 0, 0, 0);
        acc1 = MFMA16(a, b1, acc1, 0, 0, 0);
    }
    const float bb0 = pb1[ln];
    const float bb1 = pb1[16 + ln];
    const int kr = r0 >> 5;
    const int qr = ((r0 >> 4) & 1) * 2 + (q >> 1);
    const int j0 = (q & 1) * 4;
    const size_t off0 = (size_t)(i * 2 + 0) * 2048 + kr * 512 + (qr * 16 + ln) * 8 + j0;
    const size_t off1 = (size_t)(i * 2 + 1) * 2048 + kr * 512 + (qr * 16 + ln) * 8 + j0;
    ushort4 o0, o1;
    o0.x = f2bf(acc0[0] + bb0); o0.y = f2bf(acc0[1] + bb0);
    o0.z = f2bf(acc0[2] + bb0); o0.w = f2bf(acc0[3] + bb0);
    o1.x = f2bf(acc1[0] + bb1); o1.y = f2bf(acc1[1] + bb1);
    o1.z = f2bf(acc1[2] + bb1); o1.w = f2bf(acc1[3] + bb1);
    *(ushort4*)(mpF + off0) = o0;
    *(ushort4*)(mpF + off1) = o1;
}

// ---------------------------------------------------------------------------
// fused helpers
// ---------------------------------------------------------------------------
__device__ __forceinline__ void stepB(const unsigned short* Abase,
                                      const unsigned short* Bbase,
                                      f32x4 (&acc)[2][4])
{
    #pragma unroll
    for (int a = 0; a < 2; ++a)
        #pragma unroll
        for (int b = 0; b < 4; ++b)
            acc[a][b] = (f32x4){0.f, 0.f, 0.f, 0.f};
    #pragma unroll
    for (int ks = 0; ks < 4; ++ks) {
        bf16x8 av[2], bv[4];
        av[0] = *(const bf16x8*)(Abase + ks * 512);
        av[1] = *(const bf16x8*)(Abase + 2048 + ks * 512);
        #pragma unroll
        for (int bn = 0; bn < 4; ++bn)
            bv[bn] = *(const bf16x8*)(Bbase + (size_t)bn * 4096 + ks * 512);
        #pragma unroll
        for (int am = 0; am < 2; ++am)
            #pragma unroll
            for (int bn = 0; bn < 4; ++bn)
                acc[am][bn] = MFMA16(av[am], bv[bn], acc[am][bn], 0, 0, 0);
    }
}

__device__ __forceinline__ void gwrite(unsigned short* Gl, const f32x4 (&acc)[2][4],
                                       int ln, int q, int wm, int wn)
{
    #pragma unroll
    for (int am = 0; am < 2; ++am) {
        const int chunk = ln * 4 + am * 2 + (q >> 1);
        const int sig   = chunk >> 3;
        const int hbase = chunk * 264 + (q & 1) * 4;
        #pragma unroll
        for (int bn = 0; bn < 4; ++bn) {
            const int p  = (wn * 4 + bn) * 4 + wm;
            const int pp = p ^ sig;
            ushort4 g;
            g.x = f2bf(acc[am][bn][0]); g.y = f2bf(acc[am][bn][1]);
            g.z = f2bf(acc[am][bn][2]); g.w = f2bf(acc[am][bn][3]);
            *(ushort4*)(Gl + hbase + pp * 8) = g;
        }
    }
}

// ---------------------------------------------------------------------------
// fused: block = 8i x 4j (32 pairs), two d-half passes.
// ---------------------------------------------------------------------------
__global__ __launch_bounds__(512, 4) void fused_kernel(
    const float* __restrict__ x, const float* __restrict__ b2,
    const unsigned short* __restrict__ mpF, const unsigned short* __restrict__ W2f,
    float* __restrict__ out)
{
    __shared__ __align__(16) unsigned short Gl[64 * 264];  // 33792 B

    const int tid  = threadIdx.x;
    const int lane = tid & 63, w = tid >> 6;
    const int ln   = lane & 15, q = lane >> 4;
    const int wm   = w & 3, wn = w >> 2;

    const int i0 = blockIdx.x * 8;            // gridDim.x = 32
    const int j0 = blockIdx.y * 4;            // gridDim.y = 64

    f32x4 cacc0 = {0.f, 0.f, 0.f, 0.f};
    f32x4 cacc1 = {0.f, 0.f, 0.f, 0.f};

    const unsigned short* wbase = W2f + (size_t)(w * 32) * 512 + lane * 8;
    const unsigned short* Abase = mpF + (size_t)((j0 + wm) * 2) * 2048 + lane * 8;
    const unsigned short* Bb0   = mpF + (size_t)((i0 + wn * 4) * 2 + 0) * 2048 + lane * 8;
    const unsigned short* Bb1   = mpF + (size_t)((i0 + wn * 4) * 2 + 1) * 2048 + lane * 8;

    f32x4 acc[2][4];
    bf16x8 wv[8];

    // ================= pass 0 =================
    stepB(Abase, Bb0, acc);
    const unsigned short* wp0 = wbase;
    #pragma unroll
    for (int k8 = 0; k8 < 8; ++k8)                 // prefetch W2 first half
        wv[k8] = *(const bf16x8*)(wp0 + k8 * 512);
    gwrite(Gl, acc, ln, q, wm, wn);
    __syncthreads();

    #pragma unroll
    for (int ks = 0; ks < 16; ++ks) {              // step C pass 0
        bf16x8 cur = wv[ks & 7];
        if (ks < 8) wv[ks & 7] = *(const bf16x8*)(wp0 + (ks + 8) * 512);
        const int chunk = ks * 4 + q;
        const int sig   = chunk >> 3;
        const unsigned short* gp = Gl + chunk * 264 + (ln ^ sig) * 8;
        bf16x8 ag0 = *(const bf16x8*)gp;
        bf16x8 ag1 = *(const bf16x8*)(gp + 128);
        cacc0 = MFMA16(ag0, cur, cacc0, 0, 0, 0);
        cacc1 = MFMA16(ag1, cur, cacc1, 0, 0, 0);
    }

    // ================= pass 1 =================
    stepB(Abase, Bb1, acc);                        // registers only: before barrier
    __syncthreads();                               // Gl free (all waves done C0)
    const unsigned short* wp1 = wbase + (size_t)16 * 512;
    #pragma unroll
    for (int k8 = 0; k8 < 8; ++k8)
        wv[k8] = *(const bf16x8*)(wp1 + k8 * 512);
    gwrite(Gl, acc, ln, q, wm, wn);
    __syncthreads();

    // prefetch x for the coalesced epilogue
    const int f0 = tid,        p0 = f0 >> 5, kq0 = f0 & 31;
    const int f1 = 512 + tid,  p1 = f1 >> 5, kq1 = f1 & 31;
    const size_t gb0 = ((size_t)(i0 + (p0 >> 2)) * 256 + (j0 + (p0 & 3))) * 128 + kq0 * 4;
    const size_t gb1 = ((size_t)(i0 + (p1 >> 2)) * 256 + (j0 + (p1 & 3))) * 128 + kq1 * 4;
    const float4 xv0 = *(const float4*)(x + gb0);
    const float4 xv1 = *(const float4*)(x + gb1);

    #pragma unroll
    for (int ks = 0; ks < 16; ++ks) {              // step C pass 1
        bf16x8 cur = wv[ks & 7];
        if (ks < 8) wv[ks & 7] = *(const bf16x8*)(wp1 + (ks + 8) * 512);
        const int chunk = ks * 4 + q;
        const int sig   = chunk >> 3;
        const unsigned short* gp = Gl + chunk * 264 + (ln ^ sig) * 8;
        bf16x8 ag0 = *(const bf16x8*)gp;
        bf16x8 ag1 = *(const bf16x8*)(gp + 128);
        cacc0 = MFMA16(ag0, cur, cacc0, 0, 0, 0);
        cacc1 = MFMA16(ag1, cur, cacc1, 0, 0, 0);
    }
    __syncthreads();                               // Gl free (all waves done C1)

    // ---------------- coalesced epilogue via LDS transpose ----------------
    float* Ep = (float*)Gl;                        // 32 x 132 f32 = 16896 B
    const float invR = 1.0f / 128.0f;
    const int kk = w * 16 + ln;
    #pragma unroll
    for (int rg = 0; rg < 4; ++rg) {
        Ep[(q * 4 + rg) * 132 + kk]        = cacc0[rg] * invR;
        Ep[(16 + q * 4 + rg) * 132 + kk]   = cacc1[rg] * invR;
    }
    __syncthreads();

    {
        const float4 v  = *(const float4*)(Ep + p0 * 132 + kq0 * 4);
        const float4 bv = *(const float4*)(b2 + kq0 * 4);
        float4 o;
        o.x = xv0.x + v.x + bv.x; o.y = xv0.y + v.y + bv.y;
        o.z = xv0.z + v.z + bv.z; o.w = xv0.w + v.w + bv.w;
        *(float4*)(out + gb0) = o;
    }
    {
        const float4 v  = *(const float4*)(Ep + p1 * 132 + kq1 * 4);
        const float4 bv = *(const float4*)(b2 + kq1 * 4);
        float4 o;
        o.x = xv1.x + v.x + bv.x; o.y = xv1.y + v.y + bv.y;
        o.z = xv1.z + v.z + bv.z; o.w = xv1.w + v.w + bv.w;
        *(float4*)(out + gb1) = o;
    }
}

extern "C" void kernel_launch(void* const* d_in, const int* in_sizes, int n_in,
                              void* d_out, int out_size, void* d_ws, size_t ws_size,
                              hipStream_t stream) {
    const float* x  = (const float*)d_in[0];
    const float* m  = (const float*)d_in[1];
    const float* W1 = (const float*)d_in[2];
    const float* b1 = (const float*)d_in[3];
    const float* W2 = (const float*)d_in[4];
    const float* b2 = (const float*)d_in[5];
    float* out = (float*)d_out;

    unsigned short* mpF = (unsigned short*)d_ws;               // 512*2048 h = 2 MB
    unsigned short* W2f = mpF + (size_t)512 * 2048;            // 131072 h = 256 KB

    prep_kernel<<<dim3(576), dim3(256), 0, stream>>>(m, W1, b1, W2, mpF, W2f);
    fused_kernel<<<dim3(32, 64), dim3(512), 0, stream>>>(x, b2, mpF, W2f, out);
}

// Round 5
// 138.437 us; speedup vs baseline: 1.9772x; 1.0825x over previous
//
#include <hip/hip_runtime.h>
#include <stdint.h>

// B=1, R=128, L=256, IN=128, DM=32, DIM=128
// out[i,j,k] = x[i,j,k] + (1/R)*sum_{r,c,d} mp[r,j,c]*mp[r,i,d]*W2[k,c*32+d] + b2[k]
// mp[r,i,d]  = sum_e m[r,i,e]*W1[d,e] + b1[d]
//
// mpF[rt][kr][lane][j]  rt=(i*32+d)>>4 (512), kr=r>>5 (4):
//     value mp[r = kr*32 + (lane>>4)*8 + j][row = rt*16 + (lane&15)]
// W2f[nt][kc][lane][j]  nt=kout>>4 (8), kc=d (32):
//     value W2t[kout=nt*16+(lane&15)][cd' = kc*32 + (lane>>4)*8 + j]
// Block = i-tile 8 x j-tile 8 (64 pairs), 1024 blocks. Per d-half: B staged in
// LDS (32 KB, dup-free); per (d-half, j-half): stepB (A global, B LDS) -> G in
// LDS (32 pairs x 512 kloc, XOR-swizzled, stride 256) -> stepC (kout16/wave).

typedef __attribute__((ext_vector_type(8))) short bf16x8;
typedef __attribute__((ext_vector_type(4))) float f32x4;

#define MFMA16 __builtin_amdgcn_mfma_f32_16x16x32_bf16

__device__ __forceinline__ unsigned short f2bf(float f) {
    union { float f; unsigned int u; } x; x.f = f;
    unsigned int r = (x.u + 0x7fffu + ((x.u >> 16) & 1u)) >> 16;  // RNE
    return (unsigned short)r;
}

__device__ __forceinline__ bf16x8 load8f_bf(const float* p) {
    float4 v0 = *(const float4*)p;
    float4 v1 = *(const float4*)(p + 4);
    union { bf16x8 v; unsigned short u[8]; } r;
    r.u[0] = f2bf(v0.x); r.u[1] = f2bf(v0.y); r.u[2] = f2bf(v0.z); r.u[3] = f2bf(v0.w);
    r.u[4] = f2bf(v1.x); r.u[5] = f2bf(v1.y); r.u[6] = f2bf(v1.z); r.u[7] = f2bf(v1.w);
    return r.v;
}

// ---------------------------------------------------------------------------
// prep: blocks 0..511 -> mp GEMM -> mpF; blocks 512..575 -> W2 -> W2f
// ---------------------------------------------------------------------------
__global__ __launch_bounds__(256) void prep_kernel(
    const float* __restrict__ m, const float* __restrict__ W1,
    const float* __restrict__ pb1, const float* __restrict__ W2,
    unsigned short* __restrict__ mpF, unsigned short* __restrict__ W2f)
{
    const int bx = blockIdx.x;
    if (bx >= 512) {
        const int t    = (bx - 512) * 256 + threadIdx.x;   // 0..16383
        const int nt   = t >> 11;
        const int kc   = (t >> 6) & 31;
        const int lane = t & 63;
        const int ln   = lane & 15, q = lane >> 4;
        const float* src = W2 + (size_t)(nt * 16 + ln) * 1024 + kc;
        union { bf16x8 v; unsigned short u[8]; } r;
        #pragma unroll
        for (int j = 0; j < 8; ++j)
            r.u[j] = f2bf(src[(q * 8 + j) * 32]);
        *(bf16x8*)(W2f + (size_t)t * 8) = r.v;
        return;
    }
    const int lane = threadIdx.x & 63;
    const int w    = threadIdx.x >> 6;
    const int ln   = lane & 15, q = lane >> 4;
    const int tile = bx * 4 + w;          // 0..2047
    const int i    = tile >> 3;           // 0..255
    const int r0   = (tile & 7) * 16;     // r-tile base

    const float* Ap  = m  + ((size_t)(r0 + ln) * 256 + i) * 128 + q * 8;
    const float* Bp0 = W1 + (size_t)ln * 128 + q * 8;
    const float* Bp1 = W1 + (size_t)(16 + ln) * 128 + q * 8;

    f32x4 acc0 = {0.f, 0.f, 0.f, 0.f};
    f32x4 acc1 = {0.f, 0.f, 0.f, 0.f};
    #pragma unroll
    for (int ke = 0; ke < 4; ++ke) {
        bf16x8 a  = load8f_bf(Ap  + ke * 32);
        bf16x8 b0 = load8f_bf(Bp0 + ke * 32);
        bf16x8 b1 = load8f_bf(Bp1 + ke * 32);
        acc0 = MFMA16(a, b0, acc0, 0, 0, 0);
        acc1 = MFMA16(a, b1, acc1, 0, 0, 0);
    }
    const float bb0 = pb1[ln];
    const float bb1 = pb1[16 + ln];
    const int kr = r0 >> 5;
    const int qr = ((r0 >> 4) & 1) * 2 + (q >> 1);
    const int j0 = (q & 1) * 4;
    const size_t off0 = (size_t)(i * 2 + 0) * 2048 + kr * 512 + (qr * 16 + ln) * 8 + j0;
    const size_t off1 = (size_t)(i * 2 + 1) * 2048 + kr * 512 + (qr * 16 + ln) * 8 + j0;
    ushort4 o0, o1;
    o0.x = f2bf(acc0[0] + bb0); o0.y = f2bf(acc0[1] + bb0);
    o0.z = f2bf(acc0[2] + bb0); o0.w = f2bf(acc0[3] + bb0);
    o1.x = f2bf(acc1[0] + bb1); o1.y = f2bf(acc1[1] + bb1);
    o1.z = f2bf(acc1[2] + bb1); o1.w = f2bf(acc1[3] + bb1);
    *(ushort4*)(mpF + off0) = o0;
    *(ushort4*)(mpF + off1) = o1;
}

// ---------------------------------------------------------------------------
// fused helpers
// ---------------------------------------------------------------------------
__device__ __forceinline__ void stage_load(const unsigned short* __restrict__ mpF,
                                           int i0, int dhalf, int tid, uint4 (&stg)[4])
{
    #pragma unroll
    for (int r = 0; r < 4; ++r) {
        const int cid = r * 512 + tid;            // 0..2047 (16B chunks)
        const int it  = cid >> 8;                 // i-slot 0..7
        const int pos = cid & 255;                // 16B unit within 4KB row
        stg[r] = *(const uint4*)(mpF + (size_t)((i0 + it) * 2 + dhalf) * 2048 + pos * 8);
    }
}

__device__ __forceinline__ void stage_store(unsigned short* __restrict__ Bs,
                                            int tid, const uint4 (&stg)[4])
{
    #pragma unroll
    for (int r = 0; r < 4; ++r) {
        const int cid = r * 512 + tid;
        const int it  = cid >> 8;
        const int pos = cid & 255;
        *(uint4*)(Bs + it * 2048 + pos * 8) = stg[r];   // linear -> conflict-free
    }
}

__device__ __forceinline__ void stepB(const unsigned short* __restrict__ Ab,
                                      const unsigned short* __restrict__ Bs,
                                      int wn, int lane, f32x4 (&acc)[2][4])
{
    #pragma unroll
    for (int a = 0; a < 2; ++a)
        #pragma unroll
        for (int b = 0; b < 4; ++b)
            acc[a][b] = (f32x4){0.f, 0.f, 0.f, 0.f};
    #pragma unroll
    for (int ks = 0; ks < 4; ++ks) {
        bf16x8 av[2], bv[4];
        av[0] = *(const bf16x8*)(Ab + ks * 512);
        av[1] = *(const bf16x8*)(Ab + 2048 + ks * 512);
        #pragma unroll
        for (int bn = 0; bn < 4; ++bn)
            bv[bn] = *(const bf16x8*)(Bs + (wn * 4 + bn) * 2048 + ks * 512 + lane * 8);
        #pragma unroll
        for (int am = 0; am < 2; ++am)
            #pragma unroll
            for (int bn = 0; bn < 4; ++bn)
                acc[am][bn] = MFMA16(av[am], bv[bn], acc[am][bn], 0, 0, 0);
    }
}

__device__ __forceinline__ void gwrite(unsigned short* __restrict__ Gl,
                                       const f32x4 (&acc)[2][4],
                                       int ln, int q, int wm, int wn)
{
    #pragma unroll
    for (int am = 0; am < 2; ++am) {
        const int chunk = ln * 4 + am * 2 + (q >> 1);
        const int sig   = chunk >> 3;
        const int hbase = chunk * 256 + (q & 1) * 4;
        #pragma unroll
        for (int bn = 0; bn < 4; ++bn) {
            const int p  = (wn * 4 + bn) * 4 + wm;
            const int pp = p ^ sig;
            ushort4 g;
            g.x = f2bf(acc[am][bn][0]); g.y = f2bf(acc[am][bn][1]);
            g.z = f2bf(acc[am][bn][2]); g.w = f2bf(acc[am][bn][3]);
            *(ushort4*)(Gl + hbase + pp * 8) = g;
        }
    }
}

__device__ __forceinline__ void wpre(const unsigned short* __restrict__ wp, bf16x8 (&wv)[8])
{
    #pragma unroll
    for (int k8 = 0; k8 < 8; ++k8)
        wv[k8] = *(const bf16x8*)(wp + k8 * 512);
}

__device__ __forceinline__ void stepC(const unsigned short* __restrict__ Gl,
                                      const unsigned short* __restrict__ wp,
                                      bf16x8 (&wv)[8], int ln, int q,
                                      f32x4& c0, f32x4& c1)
{
    #pragma unroll
    for (int ks = 0; ks < 16; ++ks) {
        bf16x8 cur = wv[ks & 7];
        if (ks < 8) wv[ks & 7] = *(const bf16x8*)(wp + (ks + 8) * 512);
        const int chunk = ks * 4 + q;
        const int sig   = chunk >> 3;
        const unsigned short* gp = Gl + chunk * 256 + ((ln ^ sig) << 3);
        bf16x8 ag0 = *(const bf16x8*)gp;          // pairs 0..15
        bf16x8 ag1 = *(const bf16x8*)(gp + 128);  // pairs 16..31
        c0 = MFMA16(ag0, cur, c0, 0, 0, 0);
        c1 = MFMA16(ag1, cur, c1, 0, 0, 0);
    }
}

// ---------------------------------------------------------------------------
// fused: block = 8i x 8j (64 pairs), 2 d-halves x 2 j-halves.
// ---------------------------------------------------------------------------
__global__ __launch_bounds__(512, 4) void fused_kernel(
    const float* __restrict__ x, const float* __restrict__ b2,
    const unsigned short* __restrict__ mpF, const unsigned short* __restrict__ W2f,
    float* __restrict__ out)
{
    __shared__ __align__(16) unsigned char smem[65536];
    unsigned short* Gl = (unsigned short*)smem;            // 64 chunks x 256 shorts
    unsigned short* Bs = (unsigned short*)(smem + 32768);  // 8 i x 2048 shorts

    const int tid  = threadIdx.x;
    const int lane = tid & 63, w = tid >> 6;
    const int ln   = lane & 15, q = lane >> 4;
    const int wm   = w & 3, wn = w >> 2;

    const int i0 = blockIdx.x * 8;            // gridDim.x = 32
    const int j0 = blockIdx.y * 8;            // gridDim.y = 32

    const unsigned short* Ab0 = mpF + (size_t)((j0 + wm) * 2) * 2048 + lane * 8;
    const unsigned short* Ab1 = Ab0 + 16384;                   // +4 j rows
    const unsigned short* wp0 = W2f + (size_t)(w * 32) * 512 + lane * 8;
    const unsigned short* wp1 = wp0 + 16 * 512;

    f32x4 cacc[4];
    #pragma unroll
    for (int t = 0; t < 4; ++t) cacc[t] = (f32x4){0.f, 0.f, 0.f, 0.f};
    f32x4 acc[2][4];
    bf16x8 wv[8];
    uint4 stg[4];

    // ---- stage Bs(d0) ----
    stage_load(mpF, i0, 0, tid, stg);
    stage_store(Bs, tid, stg);
    __syncthreads();                                   // Bs(d0) ready

    // ---- (j0, d0) ----
    stepB(Ab0, Bs, wn, lane, acc);
    wpre(wp0, wv);
    gwrite(Gl, acc, ln, q, wm, wn);
    __syncthreads();                                   // Gl(j0,d0) ready
    stepC(Gl, wp0, wv, ln, q, cacc[0], cacc[1]);

    // ---- (j1, d0): stepB early (regs only) ----
    stepB(Ab1, Bs, wn, lane, acc);
    __syncthreads();                                   // Gl(j0,d0) reads done
    wpre(wp0, wv);
    gwrite(Gl, acc, ln, q, wm, wn);
    __syncthreads();                                   // Gl(j1,d0) ready
    stage_load(mpF, i0, 1, tid, stg);                  // overlap d1 staging loads
    stepC(Gl, wp0, wv, ln, q, cacc[2], cacc[3]);
    stage_store(Bs, tid, stg);                         // Bs(d0) readers done pre-B4
    __syncthreads();                                   // Bs(d1) ready + Gl reads done

    // ---- (j0, d1) ----
    stepB(Ab0, Bs, wn, lane, acc);
    wpre(wp1, wv);
    gwrite(Gl, acc, ln, q, wm, wn);
    __syncthreads();                                   // Gl(j0,d1) ready
    stepC(Gl, wp1, wv, ln, q, cacc[0], cacc[1]);

    // ---- (j1, d1) ----
    stepB(Ab1, Bs, wn, lane, acc);
    __syncthreads();                                   // Gl(j0,d1) reads done
    wpre(wp1, wv);
    gwrite(Gl, acc, ln, q, wm, wn);
    __syncthreads();                                   // Gl(j1,d1) ready

    // prefetch x while stepC runs
    float4 xv[4];
    size_t gb[4];
    #pragma unroll
    for (int e = 0; e < 4; ++e) {
        const int fid = e * 512 + tid;                 // 0..2047 float4 units
        const int po  = fid >> 5, kq = fid & 31;
        gb[e] = ((size_t)(i0 + (po >> 3)) * 256 + (j0 + (po & 7))) * 128 + kq * 4;
        xv[e] = *(const float4*)(x + gb[e]);
    }

    stepC(Gl, wp1, wv, ln, q, cacc[2], cacc[3]);
    __syncthreads();                                   // all Gl reads done -> Ep

    // ---- epilogue: LDS transpose (XOR-swizzled cols), coalesced out ----
    float* Ep = (float*)smem;                          // 64 rows x 128 floats
    const float invR = 1.0f / 128.0f;
    const int kk = w * 16 + ln;
    const int u  = kk >> 2, kl = kk & 3;
    #pragma unroll
    for (int jh = 0; jh < 2; ++jh)
        #pragma unroll
        for (int pt = 0; pt < 2; ++pt)
            #pragma unroll
            for (int rg = 0; rg < 4; ++rg) {
                const int po = (pt * 4 + q) * 8 + jh * 4 + rg;
                Ep[po * 128 + ((u ^ (po & 7)) << 2) + kl] = cacc[jh * 2 + pt][rg] * invR;
            }
    __syncthreads();

    #pragma unroll
    for (int e = 0; e < 4; ++e) {
        const int fid = e * 512 + tid;
        const int po  = fid >> 5, kq = fid & 31;
        const float4 v  = *(const float4*)(Ep + po * 128 + ((kq ^ (po & 7)) << 2));
        const float4 bv = *(const float4*)(b2 + kq * 4);
        float4 o;
        o.x = xv[e].x + v.x + bv.x; o.y = xv[e].y + v.y + bv.y;
        o.z = xv[e].z + v.z + bv.z; o.w = xv[e].w + v.w + bv.w;
        *(float4*)(out + gb[e]) = o;
    }
}

extern "C" void kernel_launch(void* const* d_in, const int* in_sizes, int n_in,
                              void* d_out, int out_size, void* d_ws, size_t ws_size,
                              hipStream_t stream) {
    const float* x  = (const float*)d_in[0];
    const float* m  = (const float*)d_in[1];
    const float* W1 = (const float*)d_in[2];
    const float* b1 = (const float*)d_in[3];
    const float* W2 = (const float*)d_in[4];
    const float* b2 = (const float*)d_in[5];
    float* out = (float*)d_out;

    unsigned short* mpF = (unsigned short*)d_ws;               // 512*2048 h = 2 MB
    unsigned short* W2f = mpF + (size_t)512 * 2048;            // 131072 h = 256 KB

    prep_kernel<<<dim3(576), dim3(256), 0, stream>>>(m, W1, b1, W2, mpF, W2f);
    fused_kernel<<<dim3(32, 32), dim3(512), 0, stream>>>(x, b2, mpF, W2f, out);
}